// Round 1
// baseline (594.224 us; speedup 1.0000x reference)
//
#include <hip/hip_runtime.h>
#include <math.h>

#define NN 80
#define MITERS 50
#define NTHREADS 512
#define NCT 20
#define ACTIVE 400   // 20x20 tiles of 4x4

// LDS layout (floats):
//  XT  [6400]: XT[a*80+i]  = x[i][a]        (transposed state)
//  TT  [6400]: TT[b*80+a]  = tgt[a][b]      (transposed tgt)
//  SRC [6400]: SRC[j*80+i] = src[i][j]      (transposed src; src symmetric anyway)
//  DL  [6400]: DL[i*80+a]  = d[i][a]
//  MM  [6400]: MM[j*80+a]  = max_b x[j,b]*tgt[a,b]
//  FR/FA/RD/AD [80 each], WSUM[16]
#define LDS_FLOATS (5 * 6400 + 4 * 80 + 16)

__global__ void __launch_bounds__(NTHREADS)
grf_kernel(const float* __restrict__ recon, const float* __restrict__ adj,
           float* __restrict__ out) {
  extern __shared__ float lds[];
  float* XT   = lds;
  float* TT   = lds + 6400;
  float* SRC  = lds + 12800;
  float* DL   = lds + 19200;
  float* MM   = lds + 25600;
  float* FR   = lds + 32000;     // recon row sums (out_features)
  float* FA   = FR + 80;         // adj row sums (adj_features)
  float* RD   = FA + 80;         // recon diag
  float* AD   = RD + 80;         // adj diag
  float* WSUM = AD + 80;

  const int t = threadIdx.x;

  // ---- precompute: row sums + diagonals ----
  if (t < 80) {
    float s = 0.f;
    for (int b = 0; b < NN; ++b) s += recon[t * NN + b];
    FR[t] = s;
    RD[t] = recon[t * NN + t];
  } else if (t < 160) {
    const int i = t - 80;
    float s = 0.f;
    for (int j = 0; j < NN; ++j) s += adj[i * NN + j];
    FA[i] = s;
    AD[i] = adj[i * NN + i];
  }
  __syncthreads();

  // ---- fill TT/SRC/DL/XT, accumulate BCE loss over upper triangle ----
  float lacc = 0.f;
  for (int f = t; f < NN * NN; f += NTHREADS) {
    const int r = f / NN, c = f % NN;
    // TT[b=r][a=c] = recon[a][b]*rd[a]*rd[b]*(a!=b)
    TT[f] = (r == c) ? 0.f : recon[c * NN + r] * RD[c] * RD[r];
    // SRC[j=r][i=c] = adj[i][j]*ad[i]*ad[j]*(i!=j)
    SRC[f] = (r == c) ? 0.f : adj[c * NN + r] * AD[c] * AD[r];
    // DL[i=r][a=c] = ad[i]*rd[a] / (|fa_i - fr_a| + 1)
    DL[f] = AD[r] * RD[c] / (fabsf(FA[r] - FR[c]) + 1.f);
    XT[f] = 1.f / NN;
    if (c >= r) {  // triu incl. diagonal: f = i*80+j with i=r, j=c
      const float tv = adj[f], p = recon[f];
      lacc -= tv * logf(p) + (1.f - tv) * logf(1.f - p);
    }
  }
  #pragma unroll
  for (int off = 32; off > 0; off >>= 1) lacc += __shfl_down(lacc, off, 64);
  if ((t & 63) == 0) WSUM[t >> 6] = lacc;
  __syncthreads();
  if (t == 0) {
    float s = 0.f;
    for (int w = 0; w < NTHREADS / 64; ++w) s += WSUM[w];
    out[0] = s / 3240.f;  // 80*81/2 upper-tri elements, mean reduction
  }
  __syncthreads();

  // ---- 50 mpm iterations ----
  const int rt = t / NCT;
  const int ct = t - rt * NCT;
  const int r0 = rt * 4;   // j-range (phase A) / i-range (phase B)
  const int c0 = ct * 4;   // a-range
  const bool act = (t < ACTIVE);

  for (int it = 0; it < MITERS; ++it) {
    // Phase A: MM[j,a] = max_b XT[b][j] * TT[b][a]
    if (act) {
      float m[4][4];
      #pragma unroll
      for (int r = 0; r < 4; ++r)
        #pragma unroll
        for (int c = 0; c < 4; ++c) m[r][c] = 0.f;  // max >= 0 (b=a term is 0)
      #pragma unroll 4
      for (int b = 0; b < NN; ++b) {
        const float4 xq = *(const float4*)(XT + b * NN + r0);
        const float4 tq = *(const float4*)(TT + b * NN + c0);
        const float xv[4] = {xq.x, xq.y, xq.z, xq.w};
        const float tv[4] = {tq.x, tq.y, tq.z, tq.w};
        #pragma unroll
        for (int r = 0; r < 4; ++r)
          #pragma unroll
          for (int c = 0; c < 4; ++c)
            m[r][c] = fmaxf(m[r][c], xv[r] * tv[c]);
      }
      #pragma unroll
      for (int r = 0; r < 4; ++r)
        *(float4*)(MM + (r0 + r) * NN + c0) =
            make_float4(m[r][0], m[r][1], m[r][2], m[r][3]);
    }
    __syncthreads();

    // Phase B: xn[i,a] = XT[a][i]*DL[i][a] + sum_j SRC[j][i]*MM[j][a]
    float xn[4][4];
    float ss = 0.f;
    if (act) {
      float acc[4][4];
      #pragma unroll
      for (int r = 0; r < 4; ++r)
        #pragma unroll
        for (int c = 0; c < 4; ++c) acc[r][c] = 0.f;
      #pragma unroll 4
      for (int j = 0; j < NN; ++j) {
        const float4 sq = *(const float4*)(SRC + j * NN + r0);
        const float4 mq = *(const float4*)(MM + j * NN + c0);
        const float sv[4] = {sq.x, sq.y, sq.z, sq.w};
        const float mv[4] = {mq.x, mq.y, mq.z, mq.w};
        #pragma unroll
        for (int r = 0; r < 4; ++r)
          #pragma unroll
          for (int c = 0; c < 4; ++c)
            acc[r][c] += sv[r] * mv[c];
      }
      float xo[4][4];  // xo[c][r] = XT[(c0+c)*80 + r0+r]
      #pragma unroll
      for (int c = 0; c < 4; ++c) {
        const float4 xq = *(const float4*)(XT + (c0 + c) * NN + r0);
        xo[c][0] = xq.x; xo[c][1] = xq.y; xo[c][2] = xq.z; xo[c][3] = xq.w;
      }
      #pragma unroll
      for (int r = 0; r < 4; ++r) {
        const float4 dq = *(const float4*)(DL + (r0 + r) * NN + c0);
        const float dv[4] = {dq.x, dq.y, dq.z, dq.w};
        #pragma unroll
        for (int c = 0; c < 4; ++c) {
          xn[r][c] = xo[c][r] * dv[c] + acc[r][c];
          ss += xn[r][c] * xn[r][c];
        }
      }
    }
    // Frobenius-norm reduction
    #pragma unroll
    for (int off = 32; off > 0; off >>= 1) ss += __shfl_down(ss, off, 64);
    if ((t & 63) == 0) WSUM[t >> 6] = ss;
    __syncthreads();
    float tot = 0.f;
    #pragma unroll
    for (int w = 0; w < NTHREADS / 64; ++w) tot += WSUM[w];
    const float inv = 1.0f / sqrtf(tot);
    if (act) {
      #pragma unroll
      for (int c = 0; c < 4; ++c)
        *(float4*)(XT + (c0 + c) * NN + r0) =
            make_float4(xn[0][c] * inv, xn[1][c] * inv,
                        xn[2][c] * inv, xn[3][c] * inv);
    }
    __syncthreads();
  }

  // ---- write assignment (un-transpose): out[1 + i*80 + a] = XT[a][i] ----
  for (int f = t; f < NN * NN; f += NTHREADS) {
    out[1 + f] = XT[(f % NN) * NN + (f / NN)];
  }
}

extern "C" void kernel_launch(void* const* d_in, const int* in_sizes, int n_in,
                              void* d_out, int out_size, void* d_ws, size_t ws_size,
                              hipStream_t stream) {
  const float* recon = (const float*)d_in[0];
  const float* adj   = (const float*)d_in[1];
  float* out = (float*)d_out;
  (void)in_sizes; (void)n_in; (void)out_size; (void)d_ws; (void)ws_size;

  const size_t lds_bytes = LDS_FLOATS * sizeof(float);  // ~129.3 KB (<160 KB/CU)
  hipFuncSetAttribute(reinterpret_cast<const void*>(grf_kernel),
                      hipFuncAttributeMaxDynamicSharedMemorySize,
                      (int)lds_bytes);
  grf_kernel<<<1, NTHREADS, lds_bytes, stream>>>(recon, adj, out);
}

// Round 2
// 558.321 us; speedup vs baseline: 1.0643x; 1.0643x over previous
//
#include <hip/hip_runtime.h>
#include <math.h>

#define NN 80
#define MITERS 50
#define NTHREADS 512
#define NCT 20
#define ACTIVE 400   // 20x20 tiles of 4x4

typedef float f32x2 __attribute__((ext_vector_type(2)));

// paired-b interleaved layout for the phase-A operands (x and tgt):
// element [row][k] lives at block (row>>2)*324 + (k>>1)*8 + (row&3)*2 + (k&1)
// -> one ds_read_b128 yields (v[b0][r0],v[b1][r0],v[b0][r1],v[b1][r1])
#define PIDX(row, k) \
  ((((row) >> 2) * 324) + (((k) >> 1) * 8) + ((((row) & 3)) << 1) + ((k) & 1))

#define MAX3(m, a, b) \
  asm("v_max3_f32 %0, %0, %1, %2" : "+v"(m) : "v"(a), "v"(b))

#define MMSTRIDE 84  // padded: breaks the 8-10 way bank conflict on MM stores

// LDS floats: XT_pp 6480 | TT_pp 6480 | SRC 6400 | DL 6400 | MM 6720 |
//             FR/FA/RD/AD 320 | WSUM 32 | LSUM 8
#define LDS_FLOATS (6480 + 6480 + 6400 + 6400 + 6720 + 320 + 32 + 8)

__global__ void __launch_bounds__(NTHREADS)
grf_kernel(const float* __restrict__ recon, const float* __restrict__ adj,
           float* __restrict__ out) {
  extern __shared__ float lds[];
  float* XT_pp = lds;                  // x state, paired layout
  float* TT_pp = XT_pp + 6480;         // tgt, paired layout
  float* SRC   = TT_pp + 6480;         // SRC[j*80+i] = src[i][j]
  float* DL    = SRC + 6400;           // DL[i*80+a]  = d[i][a]
  float* MM    = DL + 6400;            // MM[j*84+a]
  float* FR    = MM + 6720;
  float* FA    = FR + 80;
  float* RD    = FA + 80;
  float* AD    = RD + 80;
  float* WSUM  = AD + 80;              // 2 x 16 (double-buffered norm partials)
  float* LSUM  = WSUM + 32;            // loss partials

  const int t = threadIdx.x;

  // ---- row sums + diagonals ----
  if (t < 80) {
    float s = 0.f;
    for (int b = 0; b < NN; ++b) s += recon[t * NN + b];
    FR[t] = s;
    RD[t] = recon[t * NN + t];
  } else if (t < 160) {
    const int i = t - 80;
    float s = 0.f;
    for (int j = 0; j < NN; ++j) s += adj[i * NN + j];
    FA[i] = s;
    AD[i] = adj[i * NN + i];
  }
  if (t < 32) WSUM[t] = (t == 0) ? 1.0f : 0.f;  // ||x0||^2 = 1
  __syncthreads();

  // ---- fill operand arrays + BCE loss over triu ----
  float lacc = 0.f;
  for (int f = t; f < NN * NN; f += NTHREADS) {
    const int r = f / NN, c = f % NN;
    XT_pp[PIDX(r, c)] = 1.0f / NN;  // x[i=r][a=c]
    // tgt[a=r][b=c]
    TT_pp[PIDX(r, c)] = (r == c) ? 0.f : recon[r * NN + c] * RD[r] * RD[c];
    // SRC[j=r][i=c] = adj[i][j]*ad[i]*ad[j]
    SRC[f] = (r == c) ? 0.f : adj[c * NN + r] * AD[c] * AD[r];
    // DL[i=r][a=c]
    DL[f] = AD[r] * RD[c] / (fabsf(FA[r] - FR[c]) + 1.f);
    if (c >= r) {
      const float tv = adj[f], p = recon[f];
      lacc -= tv * logf(p) + (1.f - tv) * logf(1.f - p);
    }
  }
  #pragma unroll
  for (int off = 32; off > 0; off >>= 1) lacc += __shfl_down(lacc, off, 64);
  if ((t & 63) == 0) LSUM[t >> 6] = lacc;
  __syncthreads();
  if (t == 0) {
    float s = 0.f;
    for (int w = 0; w < NTHREADS / 64; ++w) s += LSUM[w];
    out[0] = s / 3240.f;  // 80*81/2
  }

  // ---- mpm iterations (2 barriers/iter, deferred normalization) ----
  const int rt = t / NCT;
  const int ct = t - rt * NCT;
  const int r0 = rt * 4;
  const int c0 = ct * 4;
  const bool act = (t < ACTIVE);
  __syncthreads();

  for (int it = 0; it < MITERS; ++it) {
    // Phase A: MM[j,a] = max_b x[j,b]*tgt[a,b], b unrolled by 2 via max3
    if (act) {
      const float* xp = XT_pp + rt * 324;
      const float* tp = TT_pp + ct * 324;
      float m[4][4] = {{0.f, 0.f, 0.f, 0.f}, {0.f, 0.f, 0.f, 0.f},
                       {0.f, 0.f, 0.f, 0.f}, {0.f, 0.f, 0.f, 0.f}};
      #pragma unroll 2
      for (int b2 = 0; b2 < NN / 2; ++b2) {
        const float4 xA = *(const float4*)(xp);
        const float4 xB = *(const float4*)(xp + 4);
        const float4 tA = *(const float4*)(tp);
        const float4 tB = *(const float4*)(tp + 4);
        xp += 8; tp += 8;
        const f32x2 xr[4] = {{xA.x, xA.y}, {xA.z, xA.w},
                             {xB.x, xB.y}, {xB.z, xB.w}};
        const f32x2 tc[4] = {{tA.x, tA.y}, {tA.z, tA.w},
                             {tB.x, tB.y}, {tB.z, tB.w}};
        #pragma unroll
        for (int r = 0; r < 4; ++r)
          #pragma unroll
          for (int c = 0; c < 4; ++c) {
            const f32x2 p = xr[r] * tc[c];
            MAX3(m[r][c], p.x, p.y);
          }
      }
      #pragma unroll
      for (int r = 0; r < 4; ++r)
        *(float4*)(MM + (r0 + r) * MMSTRIDE + c0) =
            make_float4(m[r][0], m[r][1], m[r][2], m[r][3]);
    }
    __syncthreads();

    // Phase B: xn = inv * (x*d + SRC^T @ MM), inv = 1/||x|| from last iter
    const float* WIN = WSUM + ((it & 1) << 4);
    float* WOUT = WSUM + (((it + 1) & 1) << 4);
    float tot = 0.f;
    #pragma unroll
    for (int w = 0; w < NTHREADS / 64; ++w) tot += WIN[w];
    const float inv = 1.0f / sqrtf(tot);

    float ss = 0.f;
    if (act) {
      f32x2 acc[4][2] = {};
      const float* sp = SRC + r0;
      const float* mp = MM + c0;
      #pragma unroll 4
      for (int j = 0; j < NN; ++j) {
        const float4 sq = *(const float4*)sp;
        const float4 mq = *(const float4*)mp;
        sp += NN; mp += MMSTRIDE;
        const f32x2 mv0 = {mq.x, mq.y};
        const f32x2 mv1 = {mq.z, mq.w};
        const float sv[4] = {sq.x, sq.y, sq.z, sq.w};
        #pragma unroll
        for (int r = 0; r < 4; ++r) {
          const f32x2 sb = {sv[r], sv[r]};
          acc[r][0] = __builtin_elementwise_fma(sb, mv0, acc[r][0]);
          acc[r][1] = __builtin_elementwise_fma(sb, mv1, acc[r][1]);
        }
      }
      // epilogue: d-term, scale, ss, write back
      float* xb = XT_pp + rt * 324 + ct * 16;
      const float4 q0 = *(const float4*)(xb);
      const float4 q1 = *(const float4*)(xb + 4);
      const float4 q2 = *(const float4*)(xb + 8);
      const float4 q3 = *(const float4*)(xb + 12);
      const f32x2 xo[4][2] = {{{q0.x, q0.y}, {q2.x, q2.y}},
                              {{q0.z, q0.w}, {q2.z, q2.w}},
                              {{q1.x, q1.y}, {q3.x, q3.y}},
                              {{q1.z, q1.w}, {q3.z, q3.w}}};
      f32x2 dv[4][2];
      #pragma unroll
      for (int r = 0; r < 4; ++r) {
        const float4 dq = *(const float4*)(DL + (r0 + r) * NN + c0);
        dv[r][0] = (f32x2){dq.x, dq.y};
        dv[r][1] = (f32x2){dq.z, dq.w};
      }
      const f32x2 iv = {inv, inv};
      f32x2 ss2 = {0.f, 0.f};
      f32x2 xn[4][2];
      #pragma unroll
      for (int r = 0; r < 4; ++r)
        #pragma unroll
        for (int cp = 0; cp < 2; ++cp) {
          f32x2 v = __builtin_elementwise_fma(xo[r][cp], dv[r][cp], acc[r][cp]);
          v = v * iv;
          xn[r][cp] = v;
          ss2 = __builtin_elementwise_fma(v, v, ss2);
        }
      ss = ss2.x + ss2.y;
      *(float4*)(xb)      = make_float4(xn[0][0].x, xn[0][0].y, xn[1][0].x, xn[1][0].y);
      *(float4*)(xb + 4)  = make_float4(xn[2][0].x, xn[2][0].y, xn[3][0].x, xn[3][0].y);
      *(float4*)(xb + 8)  = make_float4(xn[0][1].x, xn[0][1].y, xn[1][1].x, xn[1][1].y);
      *(float4*)(xb + 12) = make_float4(xn[2][1].x, xn[2][1].y, xn[3][1].x, xn[3][1].y);
    }
    #pragma unroll
    for (int off = 32; off > 0; off >>= 1) ss += __shfl_down(ss, off, 64);
    if ((t & 63) == 0) WOUT[t >> 6] = ss;
    __syncthreads();
  }

  // ---- exact final normalization + un-transposed output ----
  float tot = 0.f;
  #pragma unroll
  for (int w = 0; w < NTHREADS / 64; ++w) tot += WSUM[((MITERS & 1) << 4) + w];
  const float finv = 1.0f / sqrtf(tot);
  for (int f = t; f < NN * NN; f += NTHREADS) {
    out[1 + f] = XT_pp[PIDX(f / NN, f % NN)] * finv;
  }
}

extern "C" void kernel_launch(void* const* d_in, const int* in_sizes, int n_in,
                              void* d_out, int out_size, void* d_ws, size_t ws_size,
                              hipStream_t stream) {
  const float* recon = (const float*)d_in[0];
  const float* adj   = (const float*)d_in[1];
  float* out = (float*)d_out;
  (void)in_sizes; (void)n_in; (void)out_size; (void)d_ws; (void)ws_size;

  const size_t lds_bytes = LDS_FLOATS * sizeof(float);  // ~128.3 KB (<160 KB/CU)
  hipFuncSetAttribute(reinterpret_cast<const void*>(grf_kernel),
                      hipFuncAttributeMaxDynamicSharedMemorySize,
                      (int)lds_bytes);
  grf_kernel<<<1, NTHREADS, lds_bytes, stream>>>(recon, adj, out);
}